// Round 11
// baseline (193.722 us; speedup 1.0000x reference)
//
#include <hip/hip_runtime.h>

// Problem dims (fixed by reference)
#define Bq 32
#define Sq 64
#define Iq 256
#define Hq 256
#define Oq 128
#define Fq 512          // Iq + Hq
#define WPB 8           // workgroups per batch
#define NT 512          // threads per workgroup

// R11: R5's frozen critical+shadow loops (fused pre+nsq; tanhf; 102us main),
// with ONE structural change: the h-poll + x-stage moved from the loop HEAD
// (pre-barrier of step t+1) to the loop TAIL (right after shadow_t). The
// poll's first sample now issues ~300cyc after publish_t instead of after
// shadow + loop-tail, so peer publishes (visible ~450cyc after their stores)
// are caught on the FIRST sample instead of the second -- removes ~1 MALL RT
// (~900cyc) from the ~3840cyc step period. Still exactly one barrier/step.
// x-preload dropped: x_{t+1} staging is hidden inside the poll window.
// (R10 lesson: same-address in-flight polls MSHR-merge -- plain serial poll
// is optimal per-thread. R6/R8: extra poller streams/probes regress.)
//
// Overwrite safety (parity p slot, tag t+1, written at step t, overwritten
// with tag t+3 at step t+2): producer reaches critical_{t+2} only after its
// barrier end-of-(t+1), which required detecting tag t+2 from ALL peers;
// a peer publishes tag t+2 only after its barrier end-of-t, which required
// completing its tag-t+1 reads of parity p. Inductive, base t=0 trivial.
__global__ __launch_bounds__(NT, 2) void stpn_main(
    const float* __restrict__ x,     // (B,S,I)
    const float* __restrict__ w,     // (H,F)
    const float* __restrict__ wl,    // (H,F)
    const float* __restrict__ wgm,   // (H,F)
    const float* __restrict__ bias,  // (H)
    const float* __restrict__ ow,    // (O,H)
    const float* __restrict__ ob,    // (O)
    float* __restrict__ out,         // [tag(B*O) | h_fin(B*H) | f_fin(B*H*F)]
    unsigned long long* __restrict__ hb) // [2][B][H] (tag<<32|bits) slots
{
    const int blk   = blockIdx.x;
    const int b     = blk & 31;
    const int chunk = blk >> 5;       // 0..7
    const int h0    = chunk * 32;
    const int tid   = threadIdx.x;
    const int lr    = tid & 15;       // lane within row
    const int r     = tid >> 4;       // row 0..31
    const int row   = h0 + r;

    __shared__ float ti[2][Fq];       // double-buffered total_input

    // Static params + fast-weight state in registers for all 64 steps.
    float fw[32], fl[32], fg[32], ff[32];
    const size_t rowoff = (size_t)row * Fq;
#pragma unroll
    for (int j = 0; j < 8; ++j) {
        const int c = 4 * lr + 64 * j;
        *(float4*)&fw[4*j] = *(const float4*)(w   + rowoff + c);
        *(float4*)&fl[4*j] = *(const float4*)(wl  + rowoff + c);
        *(float4*)&fg[4*j] = *(const float4*)(wgm + rowoff + c);
    }
#pragma unroll
    for (int j = 0; j < 32; ++j) ff[j] = 0.f;

    const float brow = bias[row];
    const float* xb = x + (size_t)b * Sq * Iq;

    // Prologue: ti[0] = [x_0 | h_{-1}=0]  (tid 256..511 cover the h half)
    if (tid < Iq) ti[0][tid] = xb[tid];
    else          ti[0][tid] = 0.f;
    __syncthreads();

    for (int t = 0; t < Sq; ++t) {
        const int p = t & 1;
        const float* xpart = &ti[p][0];
        const float* hpart = &ti[p][Iq];

        // ---- critical (FROZEN): fused pre+nsq -> butterflies -> tanh ----
        float pre = 0.f, nsq = 0.f;
#pragma unroll
        for (int j = 0; j < 4; ++j) {
            const float4 tv = *(const float4*)&xpart[4 * lr + 64 * j];
            float tw;
            tw = fw[4*j+0] + ff[4*j+0]; pre = fmaf(tv.x, tw, pre); nsq = fmaf(tw, tw, nsq);
            tw = fw[4*j+1] + ff[4*j+1]; pre = fmaf(tv.y, tw, pre); nsq = fmaf(tw, tw, nsq);
            tw = fw[4*j+2] + ff[4*j+2]; pre = fmaf(tv.z, tw, pre); nsq = fmaf(tw, tw, nsq);
            tw = fw[4*j+3] + ff[4*j+3]; pre = fmaf(tv.w, tw, pre); nsq = fmaf(tw, tw, nsq);
        }
#pragma unroll
        for (int j = 4; j < 8; ++j) {
            const float4 tv = *(const float4*)&hpart[4 * lr + 64 * (j - 4)];
            float tw;
            tw = fw[4*j+0] + ff[4*j+0]; pre = fmaf(tv.x, tw, pre); nsq = fmaf(tw, tw, nsq);
            tw = fw[4*j+1] + ff[4*j+1]; pre = fmaf(tv.y, tw, pre); nsq = fmaf(tw, tw, nsq);
            tw = fw[4*j+2] + ff[4*j+2]; pre = fmaf(tv.z, tw, pre); nsq = fmaf(tw, tw, nsq);
            tw = fw[4*j+3] + ff[4*j+3]; pre = fmaf(tv.w, tw, pre); nsq = fmaf(tw, tw, nsq);
        }
#pragma unroll
        for (int m = 1; m < 16; m <<= 1) {
            pre += __shfl_xor(pre, m, 16);
            nsq += __shfl_xor(nsq, m, 16);
        }
        const float inv = __fdividef(1.0f, sqrtf(nsq) + 1e-16f);
        const float hn  = tanhf(fmaf(pre, inv, brow));

        // ---- publish immediately (starts peer-visibility clock) ----
        if (lr == 0) {
            const unsigned long long pk =
                ((unsigned long long)(unsigned)(t + 1) << 32) |
                (unsigned long long)__float_as_uint(hn);
            __hip_atomic_store(
                hb + (size_t)p * Bq * Hq + (size_t)b * Hq + row, pk,
                __ATOMIC_RELAXED, __HIP_MEMORY_SCOPE_AGENT);
        }

        // ---- shadow (FROZEN): f update, overlaps publish flight time ----
#pragma unroll
        for (int j = 0; j < 4; ++j) {
            const float4 tv = *(const float4*)&xpart[4 * lr + 64 * j];
            ff[4*j+0] = fmaf(fl[4*j+0], ff[4*j+0] * inv, fg[4*j+0] * (hn * tv.x));
            ff[4*j+1] = fmaf(fl[4*j+1], ff[4*j+1] * inv, fg[4*j+1] * (hn * tv.y));
            ff[4*j+2] = fmaf(fl[4*j+2], ff[4*j+2] * inv, fg[4*j+2] * (hn * tv.z));
            ff[4*j+3] = fmaf(fl[4*j+3], ff[4*j+3] * inv, fg[4*j+3] * (hn * tv.w));
        }
#pragma unroll
        for (int j = 4; j < 8; ++j) {
            const float4 tv = *(const float4*)&hpart[4 * lr + 64 * (j - 4)];
            ff[4*j+0] = fmaf(fl[4*j+0], ff[4*j+0] * inv, fg[4*j+0] * (hn * tv.x));
            ff[4*j+1] = fmaf(fl[4*j+1], ff[4*j+1] * inv, fg[4*j+1] * (hn * tv.y));
            ff[4*j+2] = fmaf(fl[4*j+2], ff[4*j+2] * inv, fg[4*j+2] * (hn * tv.z));
            ff[4*j+3] = fmaf(fl[4*j+3], ff[4*j+3] * inv, fg[4*j+3] * (hn * tv.w));
        }

        // ---- overlap stage: fill ti[p^1] with [x_{t+1} | h_t] ----
        if (t < Sq - 1) {
            if (tid < Iq) {
                ti[p ^ 1][tid] = xb[(size_t)(t + 1) * Iq + tid];
            } else {
                const int hh = tid - Iq;
                const unsigned long long* slot =
                    hb + (size_t)p * Bq * Hq + (size_t)b * Hq + hh;
                unsigned long long v;
                do {
                    v = __hip_atomic_load(slot, __ATOMIC_RELAXED,
                                          __HIP_MEMORY_SCOPE_AGENT);
                } while ((unsigned)(v >> 32) != (unsigned)(t + 1));
                ti[p ^ 1][Iq + hh] = __uint_as_float((unsigned)(v & 0xffffffffu));
            }
        }
        __syncthreads();                 // the only barrier per step
    }

    // ---- f_fin: 16 lanes x float4 per row chunk ----
    float* fo = out + Bq * Oq + Bq * Hq + (size_t)b * Hq * Fq + rowoff;
#pragma unroll
    for (int j = 0; j < 8; ++j) {
        const int c = 4 * lr + 64 * j;
        *(float4*)(fo + c) = *(const float4*)&ff[4*j];
    }

    // ---- epilogue (chunk-0 wg per batch): h_fin + tag_space ----
    if (chunk == 0) {
        if (tid < Hq) {
            const unsigned long long* slot =
                hb + (size_t)1 * Bq * Hq + (size_t)b * Hq + tid;  // t=63 -> parity 1
            unsigned long long v;
            do {
                v = __hip_atomic_load(slot, __ATOMIC_RELAXED,
                                      __HIP_MEMORY_SCOPE_AGENT);
            } while ((unsigned)(v >> 32) != (unsigned)Sq);
            const float hv = __uint_as_float((unsigned)(v & 0xffffffffu));
            ti[0][tid] = hv;                              // ti[0] is free here
            out[Bq * Oq + (size_t)b * Hq + tid] = hv;     // h_fin
        }
        __syncthreads();
        // 512 threads = 128 outputs x 4 lanes; lane l sums cols 16k+4l..+3.
        const int o = tid >> 2;
        const int l = tid & 3;
        const float* wr = ow + (size_t)o * Hq;
        float acc = 0.f;
#pragma unroll
        for (int k = 0; k < 16; ++k) {
            const int cc = 16 * k + 4 * l;
            const float4 w4 = *(const float4*)(wr + cc);
            const float4 h4 = *(const float4*)&ti[0][cc];
            acc += w4.x * h4.x + w4.y * h4.y + w4.z * h4.z + w4.w * h4.w;
        }
        acc += __shfl_xor(acc, 1, 4);
        acc += __shfl_xor(acc, 2, 4);
        if (l == 0) out[(size_t)b * Oq + o] = acc + ob[o];
    }
}

extern "C" void kernel_launch(void* const* d_in, const int* in_sizes, int n_in,
                              void* d_out, int out_size, void* d_ws, size_t ws_size,
                              hipStream_t stream)
{
    const float* x    = (const float*)d_in[0];
    const float* w    = (const float*)d_in[1];
    const float* wl   = (const float*)d_in[2];
    const float* wgm  = (const float*)d_in[3];
    const float* bias = (const float*)d_in[4];
    const float* ow   = (const float*)d_in[5];
    const float* ob   = (const float*)d_in[6];
    float* out = (float*)d_out;

    // Zero the (tag,val) h-exchange slots: 2 * B * H * 8 bytes = 128 KB.
    hipMemsetAsync(d_ws, 0, 2 * Bq * Hq * sizeof(unsigned long long), stream);

    stpn_main<<<Bq * WPB, NT, 0, stream>>>(x, w, wl, wgm, bias, ow, ob, out,
                                           (unsigned long long*)d_ws);
}